// Round 4
// baseline (213.423 us; speedup 1.0000x reference)
//
#include <hip/hip_runtime.h>

// Problem: x[T][E] f32, W[E][O] f32, bias[O] f32, lengths[B] int32.
// out[B][O] = (segment_mean(x, lengths) @ W) + bias
// T=131072, E=2048, O=1024, B=16 (derived at launch from in_sizes).
//
// Roofline: one streaming read of x (1.074 GB) => ~172 us at 6.3 TB/s.
//
// Phase 1 (seg_partial): GLOBAL 64-row chunks, exactly T/64 = 2048 blocks =
//   256 CU x 8 blocks/CU concurrency slots -> no straggler tail (R3 lesson:
//   2064 blocks left 16 stragglers at single-CU BW ~ +13 us). Boundary blocks
//   split accumulation per overlapping segment: first part -> main[g],
//   later parts -> extra[b].
// Phase 2 (reduce_p2): 16-way split deterministic reduction -> p2[b][s][e].
// Phase 3 (gemm_out): 4 segments/block (cuts W L3 re-reads 4x), folds the
//   16-way sum + 1/len into LDS staging.

#define E_DIM 2048
#define O_DIM 1024
#define RCH 64        // rows per global chunk
#define S_SPLIT 16    // phase-2 split factor
#define B_TILE 4      // segments per gemm block

typedef float v4f __attribute__((ext_vector_type(4)));

// ---------------------------------------------------------------------------
__global__ __launch_bounds__(256, 8) void seg_partial(const float* __restrict__ x,
                                                      const int* __restrict__ lengths,
                                                      int Bn, int Tn,
                                                      float* __restrict__ mainp,
                                                      float* __restrict__ extrap) {
    const int g  = blockIdx.x;
    const int r0 = g * RCH;
    const int rEnd = min(r0 + RCH, Tn);

    // owner segment of row r0 (lengths: 16 ints, L1-hot; uniform branch)
    int b = 0, segEnd = lengths[0];
    while (segEnd <= r0) { ++b; segEnd += lengths[b]; }

    const int tx = threadIdx.x;
    const v4f* p = (const v4f*)(x + (size_t)r0 * E_DIM + tx * 4);
    v4f a0 = {0.f, 0.f, 0.f, 0.f};
    v4f a1 = {0.f, 0.f, 0.f, 0.f};
    int r = r0;
    bool first = true;
    while (true) {
        const int stop = min(rEnd, segEnd);
#pragma unroll 4
        for (; r < stop; ++r) {
            v4f v0 = __builtin_nontemporal_load(p);        // x read exactly once
            v4f v1 = __builtin_nontemporal_load(p + 256);  // +1024 floats
            a0 += v0;
            a1 += v1;
            p += E_DIM / 4;
        }
        // flush current segment's part of this chunk
        float* dst = first ? (mainp + (size_t)g * E_DIM)
                           : (extrap + (size_t)b * E_DIM);
        v4f* d = (v4f*)dst + tx;
        d[0]   = a0;
        d[256] = a1;
        if (r >= rEnd) break;
        // crossed a segment boundary inside this chunk
        first = false;
        ++b; segEnd += lengths[b];
        a0 = (v4f){0.f, 0.f, 0.f, 0.f};
        a1 = (v4f){0.f, 0.f, 0.f, 0.f};
    }
}

// ---------------------------------------------------------------------------
// Segment b's main chunks are g in [ceil(start/64), floor((end-1)/64)]
// (empty when the segment lives inside one chunk it doesn't own); plus
// extra[b] iff start % 64 != 0. Fixed order => deterministic.
// grid = (E/1024, B, S_SPLIT), block = 256.
// ---------------------------------------------------------------------------
__global__ __launch_bounds__(256) void reduce_p2(const float* __restrict__ mainp,
                                                 const float* __restrict__ extrap,
                                                 const int* __restrict__ lengths,
                                                 float* __restrict__ p2) {
    const int b = blockIdx.y;
    const int s = blockIdx.z;
    int start = 0;
    for (int i = 0; i < b; ++i) start += lengths[i];
    const int end = start + lengths[b];
    const int g0 = (start + RCH - 1) / RCH;
    const int g1 = (end - 1) / RCH;                 // inclusive
    const int nch = (g1 >= g0) ? (g1 - g0 + 1) : 0;
    const int c0 = g0 + (nch * s) / S_SPLIT;
    const int c1 = g0 + (nch * (s + 1)) / S_SPLIT;

    const int col = blockIdx.x * 1024 + threadIdx.x * 4;
    v4f acc = {0.f, 0.f, 0.f, 0.f};
    const v4f* p = (const v4f*)(mainp + (size_t)c0 * E_DIM + col);
#pragma unroll 8
    for (int c = c0; c < c1; ++c) {                 // fixed order: deterministic
        acc += *p;
        p += E_DIM / 4;
    }
    if (s == 0 && (start % RCH) != 0)
        acc += *(const v4f*)(extrap + (size_t)b * E_DIM + col);
    *(v4f*)(p2 + ((size_t)(b * S_SPLIT + s)) * E_DIM + col) = acc;
}

// ---------------------------------------------------------------------------
// out[b][o] = dot(mean[b][:], W[:][o]) + bias[o]
// grid = (O/64, B/B_TILE) = 64 blocks; block = 512 = 64 outputs x 8 e-groups.
// Each W element loaded once serves B_TILE segments (4 indep accumulators).
// ---------------------------------------------------------------------------
__global__ __launch_bounds__(512) void gemm_out(const float* __restrict__ p2,
                                                const float* __restrict__ W,
                                                const float* __restrict__ bias,
                                                const int* __restrict__ lengths,
                                                float* __restrict__ out) {
    const int oc = blockIdx.x;
    const int bc = blockIdx.y;
    const int tx = threadIdx.x;
    const int olocal = tx & 63;
    const int eg     = tx >> 6;                    // 8 e-groups of 256
    const int o      = oc * 64 + olocal;

    __shared__ float m_lds[B_TILE][E_DIM];         // 32 KB
    __shared__ float red[B_TILE][8][64];           // 8 KB

    // stage B_TILE mean rows: sum 16 splits, scale by 1/len
    for (int i = tx; i < B_TILE * (E_DIM / 4); i += 512) {
        const int bb = i / (E_DIM / 4);
        const int cv = i % (E_DIM / 4);
        const int b  = bc * B_TILE + bb;
        const v4f* ps = (const v4f*)(p2 + (size_t)b * S_SPLIT * E_DIM) + cv;
        v4f m = {0.f, 0.f, 0.f, 0.f};
#pragma unroll
        for (int s2 = 0; s2 < S_SPLIT; ++s2)
            m += ps[s2 * (E_DIM / 4)];
        m *= (1.0f / (float)lengths[b]);
        ((v4f*)m_lds[bb])[cv] = m;
    }
    __syncthreads();

    float acc[B_TILE] = {0.f, 0.f, 0.f, 0.f};
    const float* wp = W + (size_t)(eg * 256) * O_DIM + o;
    const float* mp = &m_lds[0][eg * 256];
#pragma unroll 4
    for (int i = 0; i < 256; ++i) {
        const float w = wp[(size_t)i * O_DIM];
#pragma unroll
        for (int bb = 0; bb < B_TILE; ++bb)
            acc[bb] += mp[bb * E_DIM + i] * w;     // LDS broadcast reads
    }
#pragma unroll
    for (int bb = 0; bb < B_TILE; ++bb)
        red[bb][eg][olocal] = acc[bb];
    __syncthreads();

    if (tx < B_TILE * 64) {
        const int bb = tx >> 6, ol = tx & 63;
        float r = bias[oc * 64 + ol];
#pragma unroll
        for (int e2 = 0; e2 < 8; ++e2) r += red[bb][e2][ol];
        out[(size_t)(bc * B_TILE + bb) * O_DIM + oc * 64 + ol] = r;
    }
}

// ---------------------------------------------------------------------------
extern "C" void kernel_launch(void* const* d_in, const int* in_sizes, int n_in,
                              void* d_out, int out_size, void* d_ws, size_t ws_size,
                              hipStream_t stream) {
    const float* x       = (const float*)d_in[0];
    const float* W       = (const float*)d_in[1];
    const float* bias    = (const float*)d_in[2];
    const int*   lengths = (const int*)d_in[3];

    const int Bn = in_sizes[3];                 // 16
    const int On = in_sizes[2];                 // 1024
    const int En = in_sizes[1] / On;            // 2048
    const int Tn = in_sizes[0] / En;            // 131072
    (void)En; (void)out_size; (void)n_in; (void)ws_size;

    const int nChunks = (Tn + RCH - 1) / RCH;   // 2048 (exactly, T % 64 == 0)

    // workspace layout
    float* mainp = (float*)d_ws;                                 // [nChunks][E]
    float* extrap = mainp + (size_t)nChunks * E_DIM;             // [Bn][E]
    float* p2     = extrap + (size_t)Bn * E_DIM;                 // [Bn][S_SPLIT][E]

    seg_partial<<<nChunks, 256, 0, stream>>>(x, lengths, Bn, Tn, mainp, extrap);

    dim3 g2(E_DIM / 1024, Bn, S_SPLIT);
    reduce_p2<<<g2, 256, 0, stream>>>(mainp, extrap, lengths, p2);

    dim3 g3(On / 64, Bn / B_TILE);
    gemm_out<<<g3, 512, 0, stream>>>(p2, W, bias, lengths, (float*)d_out);
}